// Round 9
// baseline (311.541 us; speedup 1.0000x reference)
//
#include <hip/hip_runtime.h>

#define H 512
#define NNODES 10000
#define NEDGES 160000
#define NLAYERS 5
#define NCHUNK 4     // column chunks of 2500 rows (2.5 MB of h) -> fits every XCD's 4MB L2
#define CCAP 24      // slots per (row, chunk); P(Binom(deg<=40, 1/4) > 24) ~ 1e-11
#define RCAP (NCHUNK * CCAP)  // 96 slots per row

typedef __attribute__((ext_vector_type(8))) short short8;
typedef __attribute__((ext_vector_type(4))) float floatx4;

// ---------- helpers ----------
__device__ inline unsigned short f2bf(float v) {
    union { float f; unsigned int u; } x; x.f = v;
    unsigned int r = (x.u + 0x7fffu + ((x.u >> 16) & 1u)) >> 16;
    return (unsigned short)r;
}
__device__ inline float bf2f(unsigned short u) {
    union { unsigned int u; float f; } x; x.u = ((unsigned int)u) << 16; return x.f;
}
__device__ inline void gl_lds16(const void* g, void* l) {
    __builtin_amdgcn_global_load_lds((const __attribute__((address_space(1))) void*)g,
                                     (__attribute__((address_space(3))) void*)l, 16, 0, 0);
}

// ---------- fused prep: zero(7.84MB via int4) + cvt feat->bf16 + transpose + zero(out) ----------
#define ZB 1915   // 490,000 int4 groups / 256 (7,840,000 B = fill 160,000 + edges 7,680,000)
#define CB 5000   // 1,280,000 float4 groups / 256
#define TB 1536   // 16*16*6
#define OB 40     // ceil(10,000 / 256)

__global__ __launch_bounds__(256)
void prep_fused(int4* __restrict__ zero_base, const float* __restrict__ feat,
                unsigned short* __restrict__ x, const float* __restrict__ Wg,
                const float* __restrict__ vw1, unsigned short* __restrict__ Wt,
                float* __restrict__ outz) {
    __shared__ float tile[32][33];
    const int b = blockIdx.x;
    const int t = threadIdx.x;
    if (b < ZB) {
        int i = b * 256 + t;
        if (i < 490000) { int4 z = {0, 0, 0, 0}; zero_base[i] = z; }  // fill + edgesP
    } else if (b < ZB + CB) {
        int i = (b - ZB) * 256 + t;         // exactly 1,280,000 float4 groups
        float4 v = ((const float4*)feat)[i];
        ushort4 o;
        o.x = f2bf(v.x); o.y = f2bf(v.y); o.z = f2bf(v.z); o.w = f2bf(v.w);
        ((ushort4*)x)[i] = o;
    } else if (b < ZB + CB + TB) {
        const int bb = b - ZB - CB;         // 0..1535
        const int z = bb >> 8;              // 0..5
        const int rem = bb & 255;
        const int by = (rem >> 4) * 32;
        const int bx = (rem & 15) * 32;
        const float* in = (z < NLAYERS) ? (Wg + (size_t)z * H * H) : vw1;
        unsigned short* out = Wt + (size_t)z * H * H;
        const int tx = t & 31, ty = t >> 5; // (32,8)
        for (int i = ty; i < 32; i += 8)
            tile[i][tx] = in[(size_t)(by + i) * H + bx + tx];
        __syncthreads();
        for (int i = ty; i < 32; i += 8)
            out[(size_t)(bx + i) * H + by + tx] = f2bf(tile[tx][i]);
    } else {
        int i = (b - ZB - CB - TB) * 256 + t;
        if (i < NNODES) outz[i] = 0.f;      // head partial-sum accumulator
    }
}

// ---------- direct scatter into (row, col-chunk) buckets ----------
__global__ void edge_scatter_direct(const int* __restrict__ rows, const int* __restrict__ colsin,
                                    const float* __restrict__ valsin, int* __restrict__ fill,
                                    int2* __restrict__ edges, int n) {
    int i = blockIdx.x * blockDim.x + threadIdx.x;
    if (i < n) {
        int r = rows[i];
        int col = colsin[i];
        int ch = col / 2500;               // 0..3 (compiler magic-mul)
        int pos = atomicAdd(&fill[r * NCHUNK + ch], 1);
        if (pos < CCAP) {                  // memory-safety guard only
            int2 e; e.x = col; e.y = __float_as_int(valsin[i]);
            edges[(size_t)r * RCAP + ch * CCAP + pos] = e;
        }
    }
}

// ---------- GEMM (64x64 tile, BK=64, XOR k-slot swizzle, single-buffer) ----------
// EXACT r4/r6/r7 version (verified ~288us three times). No device-scope
// fences (r5 lesson); sync structure untouched (r0/r1 lessons).
__global__ __launch_bounds__(256)
void gemm_bf16_xcd(const unsigned short* __restrict__ A, const unsigned short* __restrict__ Bt,
                   unsigned short* __restrict__ C, const float* __restrict__ bias,
                   const float* __restrict__ w2, float* __restrict__ outp,
                   int mode, int M) {
    __shared__ __align__(16) unsigned short lsA[64 * 64];  // 8 KB
    __shared__ __align__(16) unsigned short lsB[64 * 64];  // 8 KB
    const int L = blockIdx.x;
    const int m_low = L & 7;
    const int rest = L >> 3;          // 0..159
    const int n = rest & 7;           // 0..7
    const int m_high = rest >> 3;     // 0..19
    const int m = m_high * 8 + m_low; // 0..159
    const int tileM = m * 64, tileN = n * 64;

    const int t = threadIdx.x;
    const int lane = t & 63;
    const int wave = t >> 6;
    const int wm = wave >> 1, wn = wave & 1;
    const int quad = lane >> 4, r16 = lane & 15;

    floatx4 acc[2][2] = {};

    const unsigned short* ap[2];
#pragma unroll
    for (int q = 0; q < 2; ++q) {
        const int c = t + 256 * q;      // 0..511
        const int row = c >> 3;         // 0..63
        int g = tileM + row; if (g >= M) g = M - 1;
        ap[q] = A + (size_t)g * 512 + (((c & 7) ^ (row & 7)) * 8);
    }
    const unsigned short* bp[2];
#pragma unroll
    for (int q = 0; q < 2; ++q) {
        const int c = t + 256 * q;
        const int row = c >> 3;
        bp[q] = Bt + (size_t)(tileN + row) * 512 + (((c & 7) ^ (row & 7)) * 8);
    }

    for (int k0 = 0; k0 < 512; k0 += 64) {
        gl_lds16(ap[0] + k0, lsA + (size_t)t * 8);
        gl_lds16(ap[1] + k0, lsA + (size_t)(t + 256) * 8);
        gl_lds16(bp[0] + k0, lsB + (size_t)t * 8);
        gl_lds16(bp[1] + k0, lsB + (size_t)(t + 256) * 8);
        __syncthreads();

        short8 af[2][2], bfr[2][2];
#pragma unroll
        for (int i = 0; i < 2; ++i) {
            const int row = wm * 32 + i * 16 + r16;
#pragma unroll
            for (int kk = 0; kk < 2; ++kk) {
                const int kcw = kk * 4 + quad;
                af[i][kk] = *(const short8*)&lsA[(size_t)(row * 8 + (kcw ^ (row & 7))) * 8];
            }
        }
#pragma unroll
        for (int j = 0; j < 2; ++j) {
            const int row = wn * 32 + j * 16 + r16;
#pragma unroll
            for (int kk = 0; kk < 2; ++kk) {
                const int kcw = kk * 4 + quad;
                bfr[j][kk] = *(const short8*)&lsB[(size_t)(row * 8 + (kcw ^ (row & 7))) * 8];
            }
        }
#pragma unroll
        for (int kk = 0; kk < 2; ++kk)  // K ascending -> numerics identical to baseline
#pragma unroll
            for (int i = 0; i < 2; ++i)
#pragma unroll
                for (int j = 0; j < 2; ++j)
                    acc[i][j] = __builtin_amdgcn_mfma_f32_16x16x32_bf16(af[i][kk], bfr[j][kk], acc[i][j], 0, 0, 0);
        __syncthreads();
    }

    if (mode == 2) {
        float part[2][4] = {};
#pragma unroll
        for (int i = 0; i < 2; ++i) {
#pragma unroll
            for (int j = 0; j < 2; ++j) {
                const int col = tileN + wn * 32 + j * 16 + r16;
                const float bcol = bias[col];
                const float wcol = w2[col];
#pragma unroll
                for (int reg = 0; reg < 4; ++reg) {
                    float v = fmaxf(acc[i][j][reg] + bcol, 0.f);
                    part[i][reg] += v * wcol;
                }
            }
        }
#pragma unroll
        for (int off = 1; off <= 8; off <<= 1)
#pragma unroll
            for (int i = 0; i < 2; ++i)
#pragma unroll
                for (int reg = 0; reg < 4; ++reg)
                    part[i][reg] += __shfl_xor(part[i][reg], off, 64);
        if (r16 == 0) {
#pragma unroll
            for (int i = 0; i < 2; ++i)
#pragma unroll
                for (int reg = 0; reg < 4; ++reg) {
                    const int row = tileM + wm * 32 + i * 16 + quad * 4 + reg;
                    if (row < M) atomicAdd(&outp[row], part[i][reg]);
                }
        }
    } else {
#pragma unroll
        for (int i = 0; i < 2; ++i) {
#pragma unroll
            for (int j = 0; j < 2; ++j) {
                const int col = tileN + wn * 32 + j * 16 + r16;
#pragma unroll
                for (int reg = 0; reg < 4; ++reg) {
                    const int row = tileM + wm * 32 + i * 16 + quad * 4 + reg;
                    if (row < M) C[(size_t)row * 512 + col] = f2bf(acc[i][j][reg]);
                }
            }
        }
    }
}

// ---------- SpMM + bias + relu, column-chunk swept, TWO ROWS PER WAVE ----------
// r8 change: each wave owns rows (2w, 2w+1) -- two INDEPENDENT gather chains
// interleaved. Unlike r1/r5's prefetch (which lengthened the same serial
// chain with redundant loads), this doubles per-wave MLP with zero extra
// traffic: 8 gathers (4+4) in flight per round instead of 4. Per-row edge
// order and accumulation order unchanged -> numerics band unchanged.
__global__ __launch_bounds__(256)
void spmm_pad(const int4* __restrict__ fill4, const int2* __restrict__ edges,
              const unsigned short* __restrict__ hmat,
              const float* __restrict__ bias, unsigned short* __restrict__ xout) {
    const int wave = threadIdx.x >> 6, lane = threadIdx.x & 63;
    const int rA = blockIdx.x * 8 + wave * 2;   // rows rA, rA+1; grid 1250*8 = 10000 exact
    const int rB = rA + 1;
    const int cb = lane * 8;
    const int4 fA = fill4[rA];
    const int4 fB = fill4[rB];
    int cntA[NCHUNK] = {fA.x, fA.y, fA.z, fA.w};
    int cntB[NCHUNK] = {fB.x, fB.y, fB.z, fB.w};
    float accA[8] = {0.f, 0.f, 0.f, 0.f, 0.f, 0.f, 0.f, 0.f};
    float accB[8] = {0.f, 0.f, 0.f, 0.f, 0.f, 0.f, 0.f, 0.f};

#pragma unroll
    for (int ch = 0; ch < NCHUNK; ++ch) {
        int cA = __builtin_amdgcn_readfirstlane(cntA[ch]);  // wave-uniform
        int cB = __builtin_amdgcn_readfirstlane(cntB[ch]);
        if (cA > CCAP) cA = CCAP;   // safety clamp (never taken statistically)
        if (cB > CCAP) cB = CCAP;
        int iA = rA * RCAP + ch * CCAP;
        int iB = rB * RCAP + ch * CCAP;
        const int eA = iA + ((cA + 3) & ~3);
        const int eB = iB + ((cB + 3) & ~3);
        while (iA < eA || iB < eB) {            // wave-uniform control flow
            const bool dA = iA < eA, dB = iB < eB;
            int c[8]; float v[8]; short8 g[8];
            if (dA) {
#pragma unroll
                for (int u = 0; u < 4; ++u) {
                    int2 ed = edges[iA + u];
                    c[u] = ed.x; v[u] = __int_as_float(ed.y);
                }
            }
            if (dB) {
#pragma unroll
                for (int u = 0; u < 4; ++u) {
                    int2 ed = edges[iB + u];
                    c[4 + u] = ed.x; v[4 + u] = __int_as_float(ed.y);
                }
            }
            if (dA) {
#pragma unroll
                for (int u = 0; u < 4; ++u)
                    g[u] = *(const short8*)(hmat + (size_t)c[u] * H + cb);
            }
            if (dB) {
#pragma unroll
                for (int u = 0; u < 4; ++u)
                    g[4 + u] = *(const short8*)(hmat + (size_t)c[4 + u] * H + cb);
            }
            if (dA) {
#pragma unroll
                for (int u = 0; u < 4; ++u)     // pads are exact +0
#pragma unroll
                    for (int j = 0; j < 8; ++j)
                        accA[j] += v[u] * bf2f((unsigned short)g[u][j]);
                iA += 4;
            }
            if (dB) {
#pragma unroll
                for (int u = 0; u < 4; ++u)
#pragma unroll
                    for (int j = 0; j < 8; ++j)
                        accB[j] += v[4 + u] * bf2f((unsigned short)g[4 + u][j]);
                iB += 4;
            }
        }
    }

    short8 oA, oB;
#pragma unroll
    for (int j = 0; j < 8; ++j) {
        oA[j] = (short)f2bf(fmaxf(accA[j] + bias[cb + j], 0.f));
        oB[j] = (short)f2bf(fmaxf(accB[j] + bias[cb + j], 0.f));
    }
    *(short8*)(xout + (size_t)rA * H + cb) = oA;
    *(short8*)(xout + (size_t)rB * H + cb) = oB;
}

// ---------- tail: out[r] = sigmoid(out[r] + b2) in place ----------
__global__ __launch_bounds__(256)
void sigmoid_tail(float* __restrict__ out, const float* __restrict__ b2, int n) {
    int i = blockIdx.x * blockDim.x + threadIdx.x;
    if (i < n) out[i] = 1.f / (1.f + expf(-(out[i] + b2[0])));
}

extern "C" void kernel_launch(void* const* d_in, const int* in_sizes, int n_in,
                              void* d_out, int out_size, void* d_ws, size_t ws_size,
                              hipStream_t stream) {
    (void)in_sizes; (void)n_in; (void)out_size; (void)ws_size;
    const float* feat   = (const float*)d_in[0];
    const int* adj_row  = (const int*)d_in[1];
    const int* adj_col  = (const int*)d_in[2];
    const float* adj_val= (const float*)d_in[3];
    const float* Wg     = (const float*)d_in[4];
    const float* bg     = (const float*)d_in[5];
    const float* vw1    = (const float*)d_in[6];
    const float* vb1    = (const float*)d_in[7];
    const float* vw2    = (const float*)d_in[8];
    const float* vb2    = (const float*)d_in[9];
    float* out = (float*)d_out;

    // workspace layout (bytes)
    char* ws = (char*)d_ws;
    unsigned short* x  = (unsigned short*)(ws + 0);          // 10,240,000
    unsigned short* h  = (unsigned short*)(ws + 10240000);   // 10,240,000
    unsigned short* Wt = (unsigned short*)(ws + 20480000);   // 3,145,728
    int*   fill    = (int*)(ws + 23625728);                  // 160,000 (NNODES*NCHUNK)
    int2*  edgesP  = (int2*)(ws + 23785728);                 // 7,680,000 (NNODES*RCAP int2)
    // fill..edgesP-end = contiguous 7,840,000 B (= 490,000 int4), 16B-aligned.

    // --- prep (2 dispatches) ---
    prep_fused<<<ZB + CB + TB + OB, 256, 0, stream>>>((int4*)fill, feat, x, Wg, vw1, Wt, out);
    edge_scatter_direct<<<(NEDGES + 255) / 256, 256, 0, stream>>>(adj_row, adj_col, adj_val,
                                                                  fill, edgesP, NEDGES);

    // --- layers ---
    for (int l = 0; l < NLAYERS; ++l) {
        gemm_bf16_xcd<<<1280, 256, 0, stream>>>(x, Wt + (size_t)l * H * H, h,
                                                nullptr, nullptr, nullptr, 0, NNODES);
        spmm_pad<<<NNODES / 8, 256, 0, stream>>>((const int4*)fill, edgesP, h,
                                                 bg + (size_t)l * H, x);
    }
    // head fused into the last GEMM epilogue (no h2 materialization)
    gemm_bf16_xcd<<<1280, 256, 0, stream>>>(x, Wt + (size_t)NLAYERS * H * H, nullptr,
                                            vb1, vw2, out, 2, NNODES);
    sigmoid_tail<<<(NNODES + 255) / 256, 256, 0, stream>>>(out, vb2, NNODES);
}

// Round 11
// 289.787 us; speedup vs baseline: 1.0751x; 1.0751x over previous
//
#include <hip/hip_runtime.h>

#define H 512
#define NNODES 10000
#define NEDGES 160000
#define NLAYERS 5
#define NCHUNK 4     // column chunks of 2500 rows (2.5 MB of h) -> fits every XCD's 4MB L2
#define CCAP 24      // slots per (row, chunk); P(Binom(deg<=40, 1/4) > 24) ~ 1e-11
#define RCAP (NCHUNK * CCAP)  // 96 slots per row

typedef __attribute__((ext_vector_type(8))) short short8;
typedef __attribute__((ext_vector_type(4))) float floatx4;

// ---------- helpers ----------
__device__ inline unsigned short f2bf(float v) {
    union { float f; unsigned int u; } x; x.f = v;
    unsigned int r = (x.u + 0x7fffu + ((x.u >> 16) & 1u)) >> 16;
    return (unsigned short)r;
}
__device__ inline float bf2f(unsigned short u) {
    union { unsigned int u; float f; } x; x.u = ((unsigned int)u) << 16; return x.f;
}
__device__ inline void gl_lds16(const void* g, void* l) {
    __builtin_amdgcn_global_load_lds((const __attribute__((address_space(1))) void*)g,
                                     (__attribute__((address_space(3))) void*)l, 16, 0, 0);
}

// ---------- fused prep: zero(7.84MB via int4) + cvt feat->bf16 + transpose + zero(out) ----------
#define ZB 1915   // 490,000 int4 groups / 256 (7,840,000 B = fill 160,000 + edges 7,680,000)
#define CB 5000   // 1,280,000 float4 groups / 256
#define TB 1536   // 16*16*6
#define OB 40     // ceil(10,000 / 256)

__global__ __launch_bounds__(256)
void prep_fused(int4* __restrict__ zero_base, const float* __restrict__ feat,
                unsigned short* __restrict__ x, const float* __restrict__ Wg,
                const float* __restrict__ vw1, unsigned short* __restrict__ Wt,
                float* __restrict__ outz) {
    __shared__ float tile[32][33];
    const int b = blockIdx.x;
    const int t = threadIdx.x;
    if (b < ZB) {
        int i = b * 256 + t;
        if (i < 490000) { int4 z = {0, 0, 0, 0}; zero_base[i] = z; }  // fill + edgesP
    } else if (b < ZB + CB) {
        int i = (b - ZB) * 256 + t;         // exactly 1,280,000 float4 groups
        float4 v = ((const float4*)feat)[i];
        ushort4 o;
        o.x = f2bf(v.x); o.y = f2bf(v.y); o.z = f2bf(v.z); o.w = f2bf(v.w);
        ((ushort4*)x)[i] = o;
    } else if (b < ZB + CB + TB) {
        const int bb = b - ZB - CB;         // 0..1535
        const int z = bb >> 8;              // 0..5
        const int rem = bb & 255;
        const int by = (rem >> 4) * 32;
        const int bx = (rem & 15) * 32;
        const float* in = (z < NLAYERS) ? (Wg + (size_t)z * H * H) : vw1;
        unsigned short* out = Wt + (size_t)z * H * H;
        const int tx = t & 31, ty = t >> 5; // (32,8)
        for (int i = ty; i < 32; i += 8)
            tile[i][tx] = in[(size_t)(by + i) * H + bx + tx];
        __syncthreads();
        for (int i = ty; i < 32; i += 8)
            out[(size_t)(bx + i) * H + by + tx] = f2bf(tile[tx][i]);
    } else {
        int i = (b - ZB - CB - TB) * 256 + t;
        if (i < NNODES) outz[i] = 0.f;      // head partial-sum accumulator
    }
}

// ---------- direct scatter into (row, col-chunk) buckets ----------
__global__ void edge_scatter_direct(const int* __restrict__ rows, const int* __restrict__ colsin,
                                    const float* __restrict__ valsin, int* __restrict__ fill,
                                    int2* __restrict__ edges, int n) {
    int i = blockIdx.x * blockDim.x + threadIdx.x;
    if (i < n) {
        int r = rows[i];
        int col = colsin[i];
        int ch = col / 2500;               // 0..3 (compiler magic-mul)
        int pos = atomicAdd(&fill[r * NCHUNK + ch], 1);
        if (pos < CCAP) {                  // memory-safety guard only
            int2 e; e.x = col; e.y = __float_as_int(valsin[i]);
            edges[(size_t)r * RCAP + ch * CCAP + pos] = e;
        }
    }
}

// ---------- GEMM (64x64 tile, BK=128, XOR k-slot swizzle, single-buffer) ----------
// r9/r10: BK 64 -> 128. Halves the barrier count (8 -> 4 iters) while keeping
// the PROVEN stage->barrier->compute->barrier structure (r0/r1: never touch
// sync). Swizzle generalizes 8 -> 16 slots: slot^(row&15); reads recover
// chunk kcw exactly; K ascends 0..511 -> MFMA sequence BIT-IDENTICAL to BK=64.
// LDS 32KB -> 5 blocks/CU, grid 1280 = 5/CU, all co-resident.
__global__ __launch_bounds__(256)
void gemm_bf16_xcd(const unsigned short* __restrict__ A, const unsigned short* __restrict__ Bt,
                   unsigned short* __restrict__ C, const float* __restrict__ bias,
                   const float* __restrict__ w2, float* __restrict__ outp,
                   int mode, int M) {
    __shared__ __align__(16) unsigned short lsA[64 * 128];  // 16 KB
    __shared__ __align__(16) unsigned short lsB[64 * 128];  // 16 KB
    const int L = blockIdx.x;
    const int m_low = L & 7;
    const int rest = L >> 3;          // 0..159
    const int n = rest & 7;           // 0..7
    const int m_high = rest >> 3;     // 0..19
    const int m = m_high * 8 + m_low; // 0..159
    const int tileM = m * 64, tileN = n * 64;

    const int t = threadIdx.x;
    const int lane = t & 63;
    const int wave = t >> 6;
    const int wm = wave >> 1, wn = wave & 1;
    const int quad = lane >> 4, r16 = lane & 15;

    floatx4 acc[2][2] = {};

    // staging pointers: c = t + 256q (q=0..3) covers 64 rows x 16 slots of 8 bf16
    const unsigned short* ap[4];
#pragma unroll
    for (int q = 0; q < 4; ++q) {
        const int c = t + 256 * q;      // 0..1023
        const int row = c >> 4;         // 0..63
        const int slot = c & 15;
        int g = tileM + row; if (g >= M) g = M - 1;
        ap[q] = A + (size_t)g * 512 + ((slot ^ (row & 15)) * 8);
    }
    const unsigned short* bp[4];
#pragma unroll
    for (int q = 0; q < 4; ++q) {
        const int c = t + 256 * q;
        const int row = c >> 4;
        const int slot = c & 15;
        bp[q] = Bt + (size_t)(tileN + row) * 512 + ((slot ^ (row & 15)) * 8);
    }

    for (int k0 = 0; k0 < 512; k0 += 128) {
        gl_lds16(ap[0] + k0, lsA + (size_t)t * 8);
        gl_lds16(ap[1] + k0, lsA + (size_t)(t + 256) * 8);
        gl_lds16(ap[2] + k0, lsA + (size_t)(t + 512) * 8);
        gl_lds16(ap[3] + k0, lsA + (size_t)(t + 768) * 8);
        gl_lds16(bp[0] + k0, lsB + (size_t)t * 8);
        gl_lds16(bp[1] + k0, lsB + (size_t)(t + 256) * 8);
        gl_lds16(bp[2] + k0, lsB + (size_t)(t + 512) * 8);
        gl_lds16(bp[3] + k0, lsB + (size_t)(t + 768) * 8);
        __syncthreads();

        short8 af[2][4], bfr[2][4];
#pragma unroll
        for (int i = 0; i < 2; ++i) {
            const int row = wm * 32 + i * 16 + r16;
#pragma unroll
            for (int kk = 0; kk < 4; ++kk) {
                const int kcw = kk * 4 + quad;            // slot 0..15
                af[i][kk] = *(const short8*)&lsA[(size_t)(row * 16 + (kcw ^ (row & 15))) * 8];
            }
        }
#pragma unroll
        for (int j = 0; j < 2; ++j) {
            const int row = wn * 32 + j * 16 + r16;
#pragma unroll
            for (int kk = 0; kk < 4; ++kk) {
                const int kcw = kk * 4 + quad;
                bfr[j][kk] = *(const short8*)&lsB[(size_t)(row * 16 + (kcw ^ (row & 15))) * 8];
            }
        }
#pragma unroll
        for (int kk = 0; kk < 4; ++kk)  // K ascending -> MFMA sequence bit-identical to BK=64
#pragma unroll
            for (int i = 0; i < 2; ++i)
#pragma unroll
                for (int j = 0; j < 2; ++j)
                    acc[i][j] = __builtin_amdgcn_mfma_f32_16x16x32_bf16(af[i][kk], bfr[j][kk], acc[i][j], 0, 0, 0);
        __syncthreads();
    }

    if (mode == 2) {
        float part[2][4] = {};
#pragma unroll
        for (int i = 0; i < 2; ++i) {
#pragma unroll
            for (int j = 0; j < 2; ++j) {
                const int col = tileN + wn * 32 + j * 16 + r16;
                const float bcol = bias[col];
                const float wcol = w2[col];
#pragma unroll
                for (int reg = 0; reg < 4; ++reg) {
                    float v = fmaxf(acc[i][j][reg] + bcol, 0.f);
                    part[i][reg] += v * wcol;
                }
            }
        }
#pragma unroll
        for (int off = 1; off <= 8; off <<= 1)
#pragma unroll
            for (int i = 0; i < 2; ++i)
#pragma unroll
                for (int reg = 0; reg < 4; ++reg)
                    part[i][reg] += __shfl_xor(part[i][reg], off, 64);
        if (r16 == 0) {
#pragma unroll
            for (int i = 0; i < 2; ++i)
#pragma unroll
                for (int reg = 0; reg < 4; ++reg) {
                    const int row = tileM + wm * 32 + i * 16 + quad * 4 + reg;
                    if (row < M) atomicAdd(&outp[row], part[i][reg]);
                }
        }
    } else {
#pragma unroll
        for (int i = 0; i < 2; ++i) {
#pragma unroll
            for (int j = 0; j < 2; ++j) {
                const int col = tileN + wn * 32 + j * 16 + r16;
#pragma unroll
                for (int reg = 0; reg < 4; ++reg) {
                    const int row = tileM + wm * 32 + i * 16 + quad * 4 + reg;
                    if (row < M) C[(size_t)row * 512 + col] = f2bf(acc[i][j][reg]);
                }
            }
        }
    }
}

// ---------- SpMM + bias + relu, column-chunk swept (EXACT r7 version, 283us verified) ----------
// r8 lesson: two-rows-per-wave halved TLP and doubled VGPR pressure -> -28us.
// The r1/r5/r8 trilogy says: do not add per-wave ILP here. One row per wave.
__global__ __launch_bounds__(256)
void spmm_pad(const int4* __restrict__ fill4, const int2* __restrict__ edges,
              const unsigned short* __restrict__ hmat,
              const float* __restrict__ bias, unsigned short* __restrict__ xout) {
    const int wave = threadIdx.x >> 6, lane = threadIdx.x & 63;
    const int r = blockIdx.x * 4 + wave;
    if (r >= NNODES) return;
    const int4 f4 = fill4[r];                 // one dwordx4: all 4 chunk counts
    int cnts[NCHUNK] = {f4.x, f4.y, f4.z, f4.w};
    const int cb = lane * 8;
    float acc[8] = {0.f, 0.f, 0.f, 0.f, 0.f, 0.f, 0.f, 0.f};

#pragma unroll
    for (int ch = 0; ch < NCHUNK; ++ch) {
        int cnt = __builtin_amdgcn_readfirstlane(cnts[ch]);  // wave-uniform
        const int s = r * RCAP + ch * CCAP;
        const int e = s + ((cnt + 3) & ~3);
        for (int i = s; i < e; i += 4) {
            int c[4]; float v[4]; short8 g[4];
#pragma unroll
            for (int u = 0; u < 4; ++u) {
                int2 ed = edges[i + u];
                c[u] = ed.x; v[u] = __int_as_float(ed.y);
            }
#pragma unroll
            for (int u = 0; u < 4; ++u) g[u] = *(const short8*)(hmat + (size_t)c[u] * H + cb);
#pragma unroll
            for (int u = 0; u < 4; ++u)  // pads are exact +0
#pragma unroll
                for (int j = 0; j < 8; ++j) acc[j] += v[u] * bf2f((unsigned short)g[u][j]);
        }
    }

    short8 o;
#pragma unroll
    for (int j = 0; j < 8; ++j)
        o[j] = (short)f2bf(fmaxf(acc[j] + bias[cb + j], 0.f));
    *(short8*)(xout + (size_t)r * H + cb) = o;
}

// ---------- tail: out[r] = sigmoid(out[r] + b2) in place ----------
__global__ __launch_bounds__(256)
void sigmoid_tail(float* __restrict__ out, const float* __restrict__ b2, int n) {
    int i = blockIdx.x * blockDim.x + threadIdx.x;
    if (i < n) out[i] = 1.f / (1.f + expf(-(out[i] + b2[0])));
}

extern "C" void kernel_launch(void* const* d_in, const int* in_sizes, int n_in,
                              void* d_out, int out_size, void* d_ws, size_t ws_size,
                              hipStream_t stream) {
    (void)in_sizes; (void)n_in; (void)out_size; (void)ws_size;
    const float* feat   = (const float*)d_in[0];
    const int* adj_row  = (const int*)d_in[1];
    const int* adj_col  = (const int*)d_in[2];
    const float* adj_val= (const float*)d_in[3];
    const float* Wg     = (const float*)d_in[4];
    const float* bg     = (const float*)d_in[5];
    const float* vw1    = (const float*)d_in[6];
    const float* vb1    = (const float*)d_in[7];
    const float* vw2    = (const float*)d_in[8];
    const float* vb2    = (const float*)d_in[9];
    float* out = (float*)d_out;

    // workspace layout (bytes)
    char* ws = (char*)d_ws;
    unsigned short* x  = (unsigned short*)(ws + 0);          // 10,240,000
    unsigned short* h  = (unsigned short*)(ws + 10240000);   // 10,240,000
    unsigned short* Wt = (unsigned short*)(ws + 20480000);   // 3,145,728
    int*   fill    = (int*)(ws + 23625728);                  // 160,000 (NNODES*NCHUNK)
    int2*  edgesP  = (int2*)(ws + 23785728);                 // 7,680,000 (NNODES*RCAP int2)
    // fill..edgesP-end = contiguous 7,840,000 B (= 490,000 int4), 16B-aligned.

    // --- prep (2 dispatches) ---
    prep_fused<<<ZB + CB + TB + OB, 256, 0, stream>>>((int4*)fill, feat, x, Wg, vw1, Wt, out);
    edge_scatter_direct<<<(NEDGES + 255) / 256, 256, 0, stream>>>(adj_row, adj_col, adj_val,
                                                                  fill, edgesP, NEDGES);

    // --- layers ---
    for (int l = 0; l < NLAYERS; ++l) {
        gemm_bf16_xcd<<<1280, 256, 0, stream>>>(x, Wt + (size_t)l * H * H, h,
                                                nullptr, nullptr, nullptr, 0, NNODES);
        spmm_pad<<<(NNODES + 3) / 4, 256, 0, stream>>>((const int4*)fill, edgesP, h,
                                                       bg + (size_t)l * H, x);
    }
    // head fused into the last GEMM epilogue (no h2 materialization)
    gemm_bf16_xcd<<<1280, 256, 0, stream>>>(x, Wt + (size_t)NLAYERS * H * H, nullptr,
                                            vb1, vw2, out, 2, NNODES);
    sigmoid_tail<<<(NNODES + 255) / 256, 256, 0, stream>>>(out, vb2, NNODES);
}

// Round 12
// 281.987 us; speedup vs baseline: 1.1048x; 1.0277x over previous
//
#include <hip/hip_runtime.h>

#define H 512
#define NNODES 10000
#define NEDGES 160000
#define NLAYERS 5
#define NCHUNK 4     // column chunks of 2500 rows (2.5 MB of h) -> fits every XCD's 4MB L2
#define CCAP 24      // slots per (row, chunk); P(Binom(deg<=40, 1/4) > 24) ~ 1e-11
#define RCAP (NCHUNK * CCAP)  // 96 slots per row

typedef __attribute__((ext_vector_type(8))) short short8;
typedef __attribute__((ext_vector_type(4))) float floatx4;

// ---------- helpers ----------
__device__ inline unsigned short f2bf(float v) {
    union { float f; unsigned int u; } x; x.f = v;
    unsigned int r = (x.u + 0x7fffu + ((x.u >> 16) & 1u)) >> 16;
    return (unsigned short)r;
}
__device__ inline float bf2f(unsigned short u) {
    union { unsigned int u; float f; } x; x.u = ((unsigned int)u) << 16; return x.f;
}
__device__ inline void gl_lds16(const void* g, void* l) {
    __builtin_amdgcn_global_load_lds((const __attribute__((address_space(1))) void*)g,
                                     (__attribute__((address_space(3))) void*)l, 16, 0, 0);
}

// ---------- fused prep: zero(7.84MB via int4) + cvt feat->bf16 + transpose + zero(out) ----------
#define ZB 1915   // 490,000 int4 groups / 256 (7,840,000 B = fill 160,000 + edges 7,680,000)
#define CB 5000   // 1,280,000 float4 groups / 256
#define TB 1536   // 16*16*6
#define OB 40     // ceil(10,000 / 256)

__global__ __launch_bounds__(256)
void prep_fused(int4* __restrict__ zero_base, const float* __restrict__ feat,
                unsigned short* __restrict__ x, const float* __restrict__ Wg,
                const float* __restrict__ vw1, unsigned short* __restrict__ Wt,
                float* __restrict__ outz) {
    __shared__ float tile[32][33];
    const int b = blockIdx.x;
    const int t = threadIdx.x;
    if (b < ZB) {
        int i = b * 256 + t;
        if (i < 490000) { int4 z = {0, 0, 0, 0}; zero_base[i] = z; }  // fill + edgesP
    } else if (b < ZB + CB) {
        int i = (b - ZB) * 256 + t;         // exactly 1,280,000 float4 groups
        float4 v = ((const float4*)feat)[i];
        ushort4 o;
        o.x = f2bf(v.x); o.y = f2bf(v.y); o.z = f2bf(v.z); o.w = f2bf(v.w);
        ((ushort4*)x)[i] = o;
    } else if (b < ZB + CB + TB) {
        const int bb = b - ZB - CB;         // 0..1535
        const int z = bb >> 8;              // 0..5
        const int rem = bb & 255;
        const int by = (rem >> 4) * 32;
        const int bx = (rem & 15) * 32;
        const float* in = (z < NLAYERS) ? (Wg + (size_t)z * H * H) : vw1;
        unsigned short* out = Wt + (size_t)z * H * H;
        const int tx = t & 31, ty = t >> 5; // (32,8)
        for (int i = ty; i < 32; i += 8)
            tile[i][tx] = in[(size_t)(by + i) * H + bx + tx];
        __syncthreads();
        for (int i = ty; i < 32; i += 8)
            out[(size_t)(bx + i) * H + by + tx] = f2bf(tile[tx][i]);
    } else {
        int i = (b - ZB - CB - TB) * 256 + t;
        if (i < NNODES) outz[i] = 0.f;      // head partial-sum accumulator
    }
}

// ---------- direct scatter into (row, col-chunk) buckets ----------
__global__ void edge_scatter_direct(const int* __restrict__ rows, const int* __restrict__ colsin,
                                    const float* __restrict__ valsin, int* __restrict__ fill,
                                    int2* __restrict__ edges, int n) {
    int i = blockIdx.x * blockDim.x + threadIdx.x;
    if (i < n) {
        int r = rows[i];
        int col = colsin[i];
        int ch = col / 2500;               // 0..3 (compiler magic-mul)
        int pos = atomicAdd(&fill[r * NCHUNK + ch], 1);
        if (pos < CCAP) {                  // memory-safety guard only
            int2 e; e.x = col; e.y = __float_as_int(valsin[i]);
            edges[(size_t)r * RCAP + ch * CCAP + pos] = e;
        }
    }
}

// ---------- GEMM (64x64 tile, BK=64, XOR k-slot swizzle, single-buffer) ----------
// EXACT best-verified version (r7, 283.3us). Closed hypotheses: sync-structure
// edits regress (r0/r1), BK=128 neutral (r9/r11 -- barrier drain already
// hidden at 5 blocks/CU), device-scope fences catastrophic (r5).
__global__ __launch_bounds__(256)
void gemm_bf16_xcd(const unsigned short* __restrict__ A, const unsigned short* __restrict__ Bt,
                   unsigned short* __restrict__ C, const float* __restrict__ bias,
                   const float* __restrict__ w2, float* __restrict__ outp,
                   int mode, int M) {
    __shared__ __align__(16) unsigned short lsA[64 * 64];  // 8 KB
    __shared__ __align__(16) unsigned short lsB[64 * 64];  // 8 KB
    const int L = blockIdx.x;
    const int m_low = L & 7;
    const int rest = L >> 3;          // 0..159
    const int n = rest & 7;           // 0..7
    const int m_high = rest >> 3;     // 0..19
    const int m = m_high * 8 + m_low; // 0..159
    const int tileM = m * 64, tileN = n * 64;

    const int t = threadIdx.x;
    const int lane = t & 63;
    const int wave = t >> 6;
    const int wm = wave >> 1, wn = wave & 1;
    const int quad = lane >> 4, r16 = lane & 15;

    floatx4 acc[2][2] = {};

    const unsigned short* ap[2];
#pragma unroll
    for (int q = 0; q < 2; ++q) {
        const int c = t + 256 * q;      // 0..511
        const int row = c >> 3;         // 0..63
        int g = tileM + row; if (g >= M) g = M - 1;
        ap[q] = A + (size_t)g * 512 + (((c & 7) ^ (row & 7)) * 8);
    }
    const unsigned short* bp[2];
#pragma unroll
    for (int q = 0; q < 2; ++q) {
        const int c = t + 256 * q;
        const int row = c >> 3;
        bp[q] = Bt + (size_t)(tileN + row) * 512 + (((c & 7) ^ (row & 7)) * 8);
    }

    for (int k0 = 0; k0 < 512; k0 += 64) {
        gl_lds16(ap[0] + k0, lsA + (size_t)t * 8);
        gl_lds16(ap[1] + k0, lsA + (size_t)(t + 256) * 8);
        gl_lds16(bp[0] + k0, lsB + (size_t)t * 8);
        gl_lds16(bp[1] + k0, lsB + (size_t)(t + 256) * 8);
        __syncthreads();

        short8 af[2][2], bfr[2][2];
#pragma unroll
        for (int i = 0; i < 2; ++i) {
            const int row = wm * 32 + i * 16 + r16;
#pragma unroll
            for (int kk = 0; kk < 2; ++kk) {
                const int kcw = kk * 4 + quad;
                af[i][kk] = *(const short8*)&lsA[(size_t)(row * 8 + (kcw ^ (row & 7))) * 8];
            }
        }
#pragma unroll
        for (int j = 0; j < 2; ++j) {
            const int row = wn * 32 + j * 16 + r16;
#pragma unroll
            for (int kk = 0; kk < 2; ++kk) {
                const int kcw = kk * 4 + quad;
                bfr[j][kk] = *(const short8*)&lsB[(size_t)(row * 8 + (kcw ^ (row & 7))) * 8];
            }
        }
#pragma unroll
        for (int kk = 0; kk < 2; ++kk)  // K ascending -> numerics identical to baseline
#pragma unroll
            for (int i = 0; i < 2; ++i)
#pragma unroll
                for (int j = 0; j < 2; ++j)
                    acc[i][j] = __builtin_amdgcn_mfma_f32_16x16x32_bf16(af[i][kk], bfr[j][kk], acc[i][j], 0, 0, 0);
        __syncthreads();
    }

    if (mode == 2) {
        float part[2][4] = {};
#pragma unroll
        for (int i = 0; i < 2; ++i) {
#pragma unroll
            for (int j = 0; j < 2; ++j) {
                const int col = tileN + wn * 32 + j * 16 + r16;
                const float bcol = bias[col];
                const float wcol = w2[col];
#pragma unroll
                for (int reg = 0; reg < 4; ++reg) {
                    float v = fmaxf(acc[i][j][reg] + bcol, 0.f);
                    part[i][reg] += v * wcol;
                }
            }
        }
#pragma unroll
        for (int off = 1; off <= 8; off <<= 1)
#pragma unroll
            for (int i = 0; i < 2; ++i)
#pragma unroll
                for (int reg = 0; reg < 4; ++reg)
                    part[i][reg] += __shfl_xor(part[i][reg], off, 64);
        if (r16 == 0) {
#pragma unroll
            for (int i = 0; i < 2; ++i)
#pragma unroll
                for (int reg = 0; reg < 4; ++reg) {
                    const int row = tileM + wm * 32 + i * 16 + quad * 4 + reg;
                    if (row < M) atomicAdd(&outp[row], part[i][reg]);
                }
        }
    } else {
#pragma unroll
        for (int i = 0; i < 2; ++i) {
#pragma unroll
            for (int j = 0; j < 2; ++j) {
                const int col = tileN + wn * 32 + j * 16 + r16;
#pragma unroll
                for (int reg = 0; reg < 4; ++reg) {
                    const int row = tileM + wm * 32 + i * 16 + quad * 4 + reg;
                    if (row < M) C[(size_t)row * 512 + col] = f2bf(acc[i][j][reg]);
                }
            }
        }
    }
}

// ---------- SpMM + bias + relu, column-chunk swept (EXACT r7 version, 283us verified) ----------
// r1/r5/r8 lessons: no per-wave ILP additions here -- 10k waves already
// saturate; the cost is L2 gather-service throughput.
__global__ __launch_bounds__(256)
void spmm_pad(const int4* __restrict__ fill4, const int2* __restrict__ edges,
              const unsigned short* __restrict__ hmat,
              const float* __restrict__ bias, unsigned short* __restrict__ xout) {
    const int wave = threadIdx.x >> 6, lane = threadIdx.x & 63;
    const int r = blockIdx.x * 4 + wave;
    if (r >= NNODES) return;
    const int4 f4 = fill4[r];                 // one dwordx4: all 4 chunk counts
    int cnts[NCHUNK] = {f4.x, f4.y, f4.z, f4.w};
    const int cb = lane * 8;
    float acc[8] = {0.f, 0.f, 0.f, 0.f, 0.f, 0.f, 0.f, 0.f};

#pragma unroll
    for (int ch = 0; ch < NCHUNK; ++ch) {
        int cnt = __builtin_amdgcn_readfirstlane(cnts[ch]);  // wave-uniform
        const int s = r * RCAP + ch * CCAP;
        const int e = s + ((cnt + 3) & ~3);
        for (int i = s; i < e; i += 4) {
            int c[4]; float v[4]; short8 g[4];
#pragma unroll
            for (int u = 0; u < 4; ++u) {
                int2 ed = edges[i + u];
                c[u] = ed.x; v[u] = __int_as_float(ed.y);
            }
#pragma unroll
            for (int u = 0; u < 4; ++u) g[u] = *(const short8*)(hmat + (size_t)c[u] * H + cb);
#pragma unroll
            for (int u = 0; u < 4; ++u)  // pads are exact +0
#pragma unroll
                for (int j = 0; j < 8; ++j) acc[j] += v[u] * bf2f((unsigned short)g[u][j]);
        }
    }

    short8 o;
#pragma unroll
    for (int j = 0; j < 8; ++j)
        o[j] = (short)f2bf(fmaxf(acc[j] + bias[cb + j], 0.f));
    *(short8*)(xout + (size_t)r * H + cb) = o;
}

// ---------- tail: out[r] = sigmoid(out[r] + b2) in place ----------
__global__ __launch_bounds__(256)
void sigmoid_tail(float* __restrict__ out, const float* __restrict__ b2, int n) {
    int i = blockIdx.x * blockDim.x + threadIdx.x;
    if (i < n) out[i] = 1.f / (1.f + expf(-(out[i] + b2[0])));
}

extern "C" void kernel_launch(void* const* d_in, const int* in_sizes, int n_in,
                              void* d_out, int out_size, void* d_ws, size_t ws_size,
                              hipStream_t stream) {
    (void)in_sizes; (void)n_in; (void)out_size; (void)ws_size;
    const float* feat   = (const float*)d_in[0];
    const int* adj_row  = (const int*)d_in[1];
    const int* adj_col  = (const int*)d_in[2];
    const float* adj_val= (const float*)d_in[3];
    const float* Wg     = (const float*)d_in[4];
    const float* bg     = (const float*)d_in[5];
    const float* vw1    = (const float*)d_in[6];
    const float* vb1    = (const float*)d_in[7];
    const float* vw2    = (const float*)d_in[8];
    const float* vb2    = (const float*)d_in[9];
    float* out = (float*)d_out;

    // workspace layout (bytes)
    char* ws = (char*)d_ws;
    unsigned short* x  = (unsigned short*)(ws + 0);          // 10,240,000
    unsigned short* h  = (unsigned short*)(ws + 10240000);   // 10,240,000
    unsigned short* Wt = (unsigned short*)(ws + 20480000);   // 3,145,728
    int*   fill    = (int*)(ws + 23625728);                  // 160,000 (NNODES*NCHUNK)
    int2*  edgesP  = (int2*)(ws + 23785728);                 // 7,680,000 (NNODES*RCAP int2)
    // fill..edgesP-end = contiguous 7,840,000 B (= 490,000 int4), 16B-aligned.

    // --- prep (2 dispatches) ---
    prep_fused<<<ZB + CB + TB + OB, 256, 0, stream>>>((int4*)fill, feat, x, Wg, vw1, Wt, out);
    edge_scatter_direct<<<(NEDGES + 255) / 256, 256, 0, stream>>>(adj_row, adj_col, adj_val,
                                                                  fill, edgesP, NEDGES);

    // --- layers ---
    for (int l = 0; l < NLAYERS; ++l) {
        gemm_bf16_xcd<<<1280, 256, 0, stream>>>(x, Wt + (size_t)l * H * H, h,
                                                nullptr, nullptr, nullptr, 0, NNODES);
        spmm_pad<<<(NNODES + 3) / 4, 256, 0, stream>>>((const int4*)fill, edgesP, h,
                                                       bg + (size_t)l * H, x);
    }
    // head fused into the last GEMM epilogue (no h2 materialization)
    gemm_bf16_xcd<<<1280, 256, 0, stream>>>(x, Wt + (size_t)NLAYERS * H * H, nullptr,
                                            vb1, vw2, out, 2, NNODES);
    sigmoid_tail<<<(NNODES + 255) / 256, 256, 0, stream>>>(out, vb2, NNODES);
}